// Round 9
// baseline (161.787 us; speedup 1.0000x reference)
//
#include <hip/hip_runtime.h>

// Problem constants (setup_inputs: B=256, T=16, H=W=160, sms=2 -> t=16, h=w=80)
#define T_DIM 16
#define H2 80
#define W2 80
#define SLICE (H2 * W2)          // 6400 floats per t-slice
#define SAMPLE (T_DIM * SLICE)   // 102400 floats per sample
#define PARTS 2                  // band 0: rows 0-63 (4-row strips); band 1: rows 64-79 (single)
#define BLOCK 320                // 5 waves

__device__ __forceinline__ float4 relu4(float4 v) {
    v.x = fmaxf(v.x, 0.f); v.y = fmaxf(v.y, 0.f);
    v.z = fmaxf(v.z, 0.f); v.w = fmaxf(v.w, 0.f);
    return v;
}

// Phase 1: per-sample linear sums (S0, Sx, Sy, Sq) + TV sums (h, w, t).
// Surviving model (r0..r8, 3-for-3 predictive): time ~ vector-memory bytes/CU
// (~7 TB/s effective), given (a) coalesced own-loads, (b) no cross-lane ops
// in the dep chain (r1/r3), (c) no hot-loop barriers (r7), (d) moderate VGPR
// + >=2 blocks/CU (r4). r8 (2-row strips, 1.85x bytes) = 157.3us total.
// This version: 4-ROW strips on rows 0-63 -> 96B loaded per 64B own (1.5x);
// rows 64-79 keep the single-row path (2.25x). Avg 1.65x vs r8's 1.85x.
//   h-pair coverage: band0 strip (y0..y0+3): internal (y0,y0+1),(y0+1,y0+2),
//   (y0+2,y0+3) + loaded neighbor (y0+3,y0+4), y0=0,4,..,60 -> pairs (0,1)..
//   (63,64) exactly once. band1: (64,65)..(78,79) + clamp(79)=0.
// r4-hazard mitigations: NO t-split (16-iter loop, register prev), and
// unroll 2 (not full) on the strip loop to bound VGPR live ranges.
__global__ __launch_bounds__(BLOCK) void tsr_phase1(const float* __restrict__ scores,
                                                    float* __restrict__ ws) {
    __shared__ float red[(BLOCK / 64) * 7];

    const int blk  = blockIdx.x;
    const int b    = blk / PARTS;
    const int band = blk % PARTS;
    const int tid  = threadIdx.x;
    const int lane = tid & 63;

    const float step = 2.0f / (float)(H2 - 1);   // h == w == 80 -> same step
    const float* sampBase = scores + (size_t)b * SAMPLE;

    float s0 = 0.f, sx = 0.f, sy = 0.f, sq = 0.f;
    float tvh = 0.f, tvw = 0.f, tvt = 0.f;

    const int cx = tid % 20;          // f4 column 0..19 (both modes)
    const int xb = cx * 4;
    const float xx0 = -1.0f + (float)xb * step;
    const float xx1 = xx0 + step, xx2 = xx1 + step, xx3 = xx2 + step;
    const float xs0 = xx0 * xx0, xs1 = xx1 * xx1;
    const float xs2 = xx2 * xx2, xs3 = xx3 * xx3;

    if (band == 0) {
        // ---- 4-row strip mode: rows y0 = 4*strip .. y0+3 (y0 <= 60) ----
        const int strip = tid / 20;               // 0..15
        const int y0 = strip * 4;
        const int off0 = y0 * W2 + xb;
        const int offH = off0 + 4 * W2;           // neighbor row y0+4 <= 64, always valid
        const int w0   = (cx < 19) ? off0 + 4 : off0 + 3;  // clamp -> diff 0 at row end

        float yyv[4], ysv[4];
#pragma unroll
        for (int k = 0; k < 4; ++k) {
            yyv[k] = -1.0f + (float)(y0 + k) * step;
            ysv[k] = yyv[k] * yyv[k];
        }

        float4 prev[4];
#pragma unroll
        for (int k = 0; k < 4; ++k) prev[k] = make_float4(0.f, 0.f, 0.f, 0.f);

#pragma unroll 2
        for (int t = 0; t < T_DIM; ++t) {
            const float* sl = sampBase + (size_t)t * SLICE;
            // 9 independent loads (imm-folded row offsets), then compute
            float4 v[4];
#pragma unroll
            for (int k = 0; k < 4; ++k)
                v[k] = relu4(*(const float4*)(sl + off0 + k * W2));
            const float4 hN = relu4(*(const float4*)(sl + offH));
            float wn[4];
#pragma unroll
            for (int k = 0; k < 4; ++k)
                wn[k] = fmaxf(sl[w0 + k * W2], 0.f);

            // column sums fold x-moments across the 4 rows at once
            const float c0 = (v[0].x + v[1].x) + (v[2].x + v[3].x);
            const float c1 = (v[0].y + v[1].y) + (v[2].y + v[3].y);
            const float c2 = (v[0].z + v[1].z) + (v[2].z + v[3].z);
            const float c3 = (v[0].w + v[1].w) + (v[2].w + v[3].w);
            s0 += (c0 + c1) + (c2 + c3);
            sx = fmaf(xx0, c0, sx); sx = fmaf(xx1, c1, sx);
            sx = fmaf(xx2, c2, sx); sx = fmaf(xx3, c3, sx);
            sq = fmaf(xs0, c0, sq); sq = fmaf(xs1, c1, sq);
            sq = fmaf(xs2, c2, sq); sq = fmaf(xs3, c3, sq);
#pragma unroll
            for (int k = 0; k < 4; ++k) {
                const float rs = (v[k].x + v[k].y) + (v[k].z + v[k].w);
                sy = fmaf(yyv[k], rs, sy);
                sq = fmaf(ysv[k], rs, sq);
                // w-diffs: 3 internal + boundary (0 at cx==19 via clamp)
                tvw += fabsf(v[k].y - v[k].x) + fabsf(v[k].z - v[k].y) +
                       fabsf(v[k].w - v[k].z) + fabsf(wn[k] - v[k].w);
                // h-diffs: register-local pairs + loaded neighbor at k==3
                const float4 nk = (k < 3) ? v[k + 1] : hN;
                tvh += fabsf(nk.x - v[k].x) + fabsf(nk.y - v[k].y) +
                       fabsf(nk.z - v[k].z) + fabsf(nk.w - v[k].w);
                // t-diffs: register-resident
                if (t > 0) {
                    tvt += fabsf(v[k].x - prev[k].x) + fabsf(v[k].y - prev[k].y) +
                           fabsf(v[k].z - prev[k].z) + fabsf(v[k].w - prev[k].w);
                }
                prev[k] = v[k];
            }
        }
    } else {
        // ---- single-row mode: rows 64..79 (exact r8 band-2 path) ----
        const int r = tid / 20;                   // 0..15
        const int y = 64 + r;
        const int rowOff = y * W2 + xb;
        const int hOff = (y + 1 < H2) ? rowOff + W2 : rowOff;  // clamp -> diff 0
        const int wOff = (cx < 19) ? rowOff + 4 : rowOff + 3;  // clamp -> diff 0

        const float yy = -1.0f + (float)y * step;
        const float yy2 = yy * yy;
        const float cq0 = xs0 + yy2, cq1 = xs1 + yy2;
        const float cq2 = xs2 + yy2, cq3 = xs3 + yy2;

        float4 prev = make_float4(0.f, 0.f, 0.f, 0.f);

#pragma unroll 4
        for (int t = 0; t < T_DIM; ++t) {
            const float* sl = sampBase + (size_t)t * SLICE;
            const float4 v  = relu4(*(const float4*)(sl + rowOff));
            const float4 hN = relu4(*(const float4*)(sl + hOff));
            const float  wN = fmaxf(sl[wOff], 0.f);

            const float rs = (v.x + v.y) + (v.z + v.w);
            s0 += rs;
            sy = fmaf(yy, rs, sy);
            sx = fmaf(xx0, v.x, sx); sx = fmaf(xx1, v.y, sx);
            sx = fmaf(xx2, v.z, sx); sx = fmaf(xx3, v.w, sx);
            sq = fmaf(cq0, v.x, sq); sq = fmaf(cq1, v.y, sq);
            sq = fmaf(cq2, v.z, sq); sq = fmaf(cq3, v.w, sq);

            tvw += fabsf(v.y - v.x) + fabsf(v.z - v.y) + fabsf(v.w - v.z)
                 + fabsf(wN - v.w);
            tvh += fabsf(hN.x - v.x) + fabsf(hN.y - v.y) +
                   fabsf(hN.z - v.z) + fabsf(hN.w - v.w);
            if (t > 0) {
                tvt += fabsf(v.x - prev.x) + fabsf(v.y - prev.y) +
                       fabsf(v.z - prev.z) + fabsf(v.w - prev.w);
            }
            prev = v;
        }
    }

    // block reduction: wave shuffle, then cross-wave via LDS
    float acc[7] = {s0, sx, sy, sq, tvh, tvw, tvt};
#pragma unroll
    for (int off = 32; off > 0; off >>= 1) {
#pragma unroll
        for (int i = 0; i < 7; ++i) acc[i] += __shfl_down(acc[i], off);
    }
    const int wave = tid >> 6;
    if (lane == 0) {
#pragma unroll
        for (int i = 0; i < 7; ++i) red[wave * 7 + i] = acc[i];
    }
    __syncthreads();
    if (tid < 7) {
        float s = 0.f;
#pragma unroll
        for (int wv = 0; wv < BLOCK / 64; ++wv) s += red[wv * 7 + tid];
        ws[blk * 8 + tid] = s;  // distinct slot per block -> no init, no atomics
    }
}

// Phase 2: sum the band partials per sample, nonlinear combine, batch mean
__global__ __launch_bounds__(256) void tsr_finalize(const float* __restrict__ ws,
                                                    float* __restrict__ out, int B) {
    __shared__ float red[256];
    const int tid = threadIdx.x;
    float acc = 0.f;
    const float ch = 1.0f / (float)(T_DIM * (H2 - 1) * W2);       // 1/101120
    const float cw = 1.0f / (float)(T_DIM * H2 * (W2 - 1));       // 1/101120
    const float ct = 0.3f / (float)((T_DIM - 1) * H2 * W2);       // 0.3/96000
    for (int b = tid; b < B; b += 256) {
        float p[7] = {0.f, 0.f, 0.f, 0.f, 0.f, 0.f, 0.f};
        for (int part = 0; part < PARTS; ++part) {
            const float* w = ws + (size_t)(b * PARTS + part) * 8;
#pragma unroll
            for (int i = 0; i < 7; ++i) p[i] += w[i];
        }
        const float S0 = p[0], Sx = p[1], Sy = p[2], Sq = p[3];
        const float Th = p[4], Tw = p[5], Tt = p[6];
        const float tot = fmaxf(S0, 1e-6f);
        const float inv = 1.0f / tot;
        const float mux = Sx * inv, muy = Sy * inv;
        const float m2 = mux * mux + muy * muy;
        const float compact = Sq * inv - 2.0f * m2 + m2 * (S0 * inv);
        const float tv = Th * ch + Tw * cw + Tt * ct;
        acc += compact + tv;
    }
    red[tid] = acc;
    __syncthreads();
    for (int s = 128; s > 0; s >>= 1) {
        if (tid < s) red[tid] += red[tid + s];
        __syncthreads();
    }
    if (tid == 0) out[0] = red[0] / (float)B;
}

extern "C" void kernel_launch(void* const* d_in, const int* in_sizes, int n_in,
                              void* d_out, int out_size, void* d_ws, size_t ws_size,
                              hipStream_t stream) {
    const float* scores = (const float*)d_in[0];
    const int B = in_sizes[0] / SAMPLE;  // 256
    float* ws = (float*)d_ws;

    tsr_phase1<<<B * PARTS, BLOCK, 0, stream>>>(scores, ws);
    tsr_finalize<<<1, 256, 0, stream>>>(ws, (float*)d_out, B);
}

// Round 10
// 157.287 us; speedup vs baseline: 1.0286x; 1.0286x over previous
//
#include <hip/hip_runtime.h>

// Problem constants (setup_inputs: B=256, T=16, H=W=160, sms=2 -> t=16, h=w=80)
#define T_DIM 16
#define H2 80
#define W2 80
#define SLICE (H2 * W2)          // 6400 floats per t-slice
#define SAMPLE (T_DIM * SLICE)   // 102400 floats per sample
#define PARTS 3                  // bands per sample: rows 0-31, 32-63 (2-row strips), 64-79 (single)
#define BLOCK 320                // 5 waves

__device__ __forceinline__ float4 relu4(float4 v) {
    v.x = fmaxf(v.x, 0.f); v.y = fmaxf(v.y, 0.f);
    v.z = fmaxf(v.z, 0.f); v.w = fmaxf(v.w, 0.f);
    return v;
}

// Phase 1: per-sample linear sums (S0, Sx, Sy, Sq) + TV sums (h, w, t).
// FINAL (reverted to the round-8 best: 157.3us total, phase1 ~31us).
// Surviving model (validated r0..r9): time ~ bytes through the per-CU
// vector-memory path (~10-12 B/cyc/CU), given (a) coalesced own-loads,
// (b) no cross-lane ops in the dep chain (r1/r3 regressed), (c) no hot-loop
// barriers (r7 regressed), (d) moderate VGPR + >=3 blocks/CU with balanced
// block work (r4/r9 regressed). 2-ROW REGISTER STRIPS on 64 of 80 rows:
//   bands 0,1 (rows 0-31, 32-63): thread owns rows (2s, 2s+1) at one f4-col.
//     h-diff (2s,2s+1) is register-local; only row 2s+2 is loaded (L1 hit).
//     56B/thread-iter for 32B own (1.75x) vs single-row 2.25x.
//   band 2 (rows 64-79): single-row path (ragged tail, same block size).
// h-pair coverage: band0 internal (0,1)..(30,31) + hN (1,2)..(31,32);
// band1 internal (32,33)..(62,63) + hN (33,34)..(63,64); band2 (64,65)..
// (78,79) + clamp(79)=0. Every pair 0..78 exactly once. No seed reloads,
// register t-diffs, no barriers, no shuffles.
// Deeper strips (r9, 4-row) lose more to block-granularity imbalance than
// they save in bytes; LDS exchange (r7) loses to the per-iter barrier drain.
__global__ __launch_bounds__(BLOCK) void tsr_phase1(const float* __restrict__ scores,
                                                    float* __restrict__ ws) {
    __shared__ float red[(BLOCK / 64) * 7];

    const int blk  = blockIdx.x;
    const int b    = blk / PARTS;
    const int band = blk % PARTS;
    const int tid  = threadIdx.x;
    const int lane = tid & 63;

    const float step = 2.0f / (float)(H2 - 1);   // h == w == 80 -> same step
    const float* sampBase = scores + (size_t)b * SAMPLE;

    float s0 = 0.f, sx = 0.f, sy = 0.f, sq = 0.f;
    float tvh = 0.f, tvw = 0.f, tvt = 0.f;

    const int cx = tid % 20;          // f4 column 0..19 (both modes)
    const int xb = cx * 4;
    const float xx0 = -1.0f + (float)xb * step;
    const float xx1 = xx0 + step, xx2 = xx1 + step, xx3 = xx2 + step;
    const float xs0 = xx0 * xx0, xs1 = xx1 * xx1;
    const float xs2 = xx2 * xx2, xs3 = xx3 * xx3;

    if (band < 2) {
        // ---- 2-row strip mode: rows y0 = band*32 + 2*strip, y0+1 ----
        const int strip = tid / 20;               // 0..15
        const int y0 = band * 32 + strip * 2;     // even row; max 62
        const int off0 = y0 * W2 + xb;            // own row A
        const int off1 = off0 + W2;               // own row B
        const int offH = off1 + W2;               // neighbor row (<=64, always valid)
        const int w0   = (cx < 19) ? off0 + 4 : off0 + 3;  // clamp -> diff 0
        const int w1   = w0 + W2;

        const float yyA = -1.0f + (float)y0 * step;
        const float yyB = yyA + step;
        const float ysA = yyA * yyA, ysB = yyB * yyB;

        float4 prev0 = make_float4(0.f, 0.f, 0.f, 0.f);
        float4 prev1 = prev0;

#pragma unroll 4
        for (int t = 0; t < T_DIM; ++t) {
            const float* sl = sampBase + (size_t)t * SLICE;
            // 5 independent loads (one base, imm-folded offsets), then compute
            const float4 v0 = relu4(*(const float4*)(sl + off0));
            const float4 v1 = relu4(*(const float4*)(sl + off1));
            const float4 hN = relu4(*(const float4*)(sl + offH));
            const float wn0 = fmaxf(sl[w0], 0.f);
            const float wn1 = fmaxf(sl[w1], 0.f);

            // column sums fold the x-moments for both rows at once
            const float c0 = v0.x + v1.x, c1 = v0.y + v1.y;
            const float c2 = v0.z + v1.z, c3 = v0.w + v1.w;
            const float rs0 = (v0.x + v0.y) + (v0.z + v0.w);
            const float rs1 = (v1.x + v1.y) + (v1.z + v1.w);
            s0 += (c0 + c1) + (c2 + c3);
            sx = fmaf(xx0, c0, sx); sx = fmaf(xx1, c1, sx);
            sx = fmaf(xx2, c2, sx); sx = fmaf(xx3, c3, sx);
            sy = fmaf(yyA, rs0, sy); sy = fmaf(yyB, rs1, sy);
            sq = fmaf(xs0, c0, sq); sq = fmaf(xs1, c1, sq);
            sq = fmaf(xs2, c2, sq); sq = fmaf(xs3, c3, sq);
            sq = fmaf(ysA, rs0, sq); sq = fmaf(ysB, rs1, sq);

            // w-diffs: 3 internal + boundary per row (boundary 0 at cx==19)
            tvw += fabsf(v0.y - v0.x) + fabsf(v0.z - v0.y) + fabsf(v0.w - v0.z)
                 + fabsf(wn0 - v0.w)
                 + fabsf(v1.y - v1.x) + fabsf(v1.z - v1.y) + fabsf(v1.w - v1.z)
                 + fabsf(wn1 - v1.w);

            // h-diffs: register-local pair + loaded neighbor
            tvh += fabsf(v1.x - v0.x) + fabsf(v1.y - v0.y) +
                   fabsf(v1.z - v0.z) + fabsf(v1.w - v0.w)
                 + fabsf(hN.x - v1.x) + fabsf(hN.y - v1.y) +
                   fabsf(hN.z - v1.z) + fabsf(hN.w - v1.w);

            // t-diffs: register-resident, both rows
            if (t > 0) {
                tvt += fabsf(v0.x - prev0.x) + fabsf(v0.y - prev0.y) +
                       fabsf(v0.z - prev0.z) + fabsf(v0.w - prev0.w)
                     + fabsf(v1.x - prev1.x) + fabsf(v1.y - prev1.y) +
                       fabsf(v1.z - prev1.z) + fabsf(v1.w - prev1.w);
            }
            prev0 = v0; prev1 = v1;
        }
    } else {
        // ---- single-row mode: rows 64..79 ----
        const int r = tid / 20;                   // 0..15
        const int y = 64 + r;
        const int rowOff = y * W2 + xb;
        const int hOff = (y + 1 < H2) ? rowOff + W2 : rowOff;  // clamp -> diff 0
        const int wOff = (cx < 19) ? rowOff + 4 : rowOff + 3;  // clamp -> diff 0

        const float yy = -1.0f + (float)y * step;
        const float yy2 = yy * yy;
        const float cq0 = xs0 + yy2, cq1 = xs1 + yy2;
        const float cq2 = xs2 + yy2, cq3 = xs3 + yy2;

        float4 prev = make_float4(0.f, 0.f, 0.f, 0.f);

#pragma unroll 4
        for (int t = 0; t < T_DIM; ++t) {
            const float* sl = sampBase + (size_t)t * SLICE;
            const float4 v  = relu4(*(const float4*)(sl + rowOff));
            const float4 hN = relu4(*(const float4*)(sl + hOff));
            const float  wN = fmaxf(sl[wOff], 0.f);

            const float rs = (v.x + v.y) + (v.z + v.w);
            s0 += rs;
            sy = fmaf(yy, rs, sy);
            sx = fmaf(xx0, v.x, sx); sx = fmaf(xx1, v.y, sx);
            sx = fmaf(xx2, v.z, sx); sx = fmaf(xx3, v.w, sx);
            sq = fmaf(cq0, v.x, sq); sq = fmaf(cq1, v.y, sq);
            sq = fmaf(cq2, v.z, sq); sq = fmaf(cq3, v.w, sq);

            tvw += fabsf(v.y - v.x) + fabsf(v.z - v.y) + fabsf(v.w - v.z)
                 + fabsf(wN - v.w);
            tvh += fabsf(hN.x - v.x) + fabsf(hN.y - v.y) +
                   fabsf(hN.z - v.z) + fabsf(hN.w - v.w);
            if (t > 0) {
                tvt += fabsf(v.x - prev.x) + fabsf(v.y - prev.y) +
                       fabsf(v.z - prev.z) + fabsf(v.w - prev.w);
            }
            prev = v;
        }
    }

    // block reduction: wave shuffle, then cross-wave via LDS
    float acc[7] = {s0, sx, sy, sq, tvh, tvw, tvt};
#pragma unroll
    for (int off = 32; off > 0; off >>= 1) {
#pragma unroll
        for (int i = 0; i < 7; ++i) acc[i] += __shfl_down(acc[i], off);
    }
    const int wave = tid >> 6;
    if (lane == 0) {
#pragma unroll
        for (int i = 0; i < 7; ++i) red[wave * 7 + i] = acc[i];
    }
    __syncthreads();
    if (tid < 7) {
        float s = 0.f;
#pragma unroll
        for (int wv = 0; wv < BLOCK / 64; ++wv) s += red[wv * 7 + tid];
        ws[blk * 8 + tid] = s;  // distinct slot per block -> no init, no atomics
    }
}

// Phase 2: sum the 3 band partials per sample, nonlinear combine, batch mean
__global__ __launch_bounds__(256) void tsr_finalize(const float* __restrict__ ws,
                                                    float* __restrict__ out, int B) {
    __shared__ float red[256];
    const int tid = threadIdx.x;
    float acc = 0.f;
    const float ch = 1.0f / (float)(T_DIM * (H2 - 1) * W2);       // 1/101120
    const float cw = 1.0f / (float)(T_DIM * H2 * (W2 - 1));       // 1/101120
    const float ct = 0.3f / (float)((T_DIM - 1) * H2 * W2);       // 0.3/96000
    for (int b = tid; b < B; b += 256) {
        float p[7] = {0.f, 0.f, 0.f, 0.f, 0.f, 0.f, 0.f};
        for (int part = 0; part < PARTS; ++part) {
            const float* w = ws + (size_t)(b * PARTS + part) * 8;
#pragma unroll
            for (int i = 0; i < 7; ++i) p[i] += w[i];
        }
        const float S0 = p[0], Sx = p[1], Sy = p[2], Sq = p[3];
        const float Th = p[4], Tw = p[5], Tt = p[6];
        const float tot = fmaxf(S0, 1e-6f);
        const float inv = 1.0f / tot;
        const float mux = Sx * inv, muy = Sy * inv;
        const float m2 = mux * mux + muy * muy;
        const float compact = Sq * inv - 2.0f * m2 + m2 * (S0 * inv);
        const float tv = Th * ch + Tw * cw + Tt * ct;
        acc += compact + tv;
    }
    red[tid] = acc;
    __syncthreads();
    for (int s = 128; s > 0; s >>= 1) {
        if (tid < s) red[tid] += red[tid + s];
        __syncthreads();
    }
    if (tid == 0) out[0] = red[0] / (float)B;
}

extern "C" void kernel_launch(void* const* d_in, const int* in_sizes, int n_in,
                              void* d_out, int out_size, void* d_ws, size_t ws_size,
                              hipStream_t stream) {
    const float* scores = (const float*)d_in[0];
    const int B = in_sizes[0] / SAMPLE;  // 256
    float* ws = (float*)d_ws;

    tsr_phase1<<<B * PARTS, BLOCK, 0, stream>>>(scores, ws);
    tsr_finalize<<<1, 256, 0, stream>>>(ws, (float*)d_out, B);
}